// Round 3
// baseline (351.019 us; speedup 1.0000x reference)
//
#include <hip/hip_runtime.h>
#include <math.h>

// Problem constants (from setup_inputs)
#define N_DET 512
#define K_ANN 100
#define MH    28
#define MW    28
#define NPIX  (MH * MW)     // 784
#define IMH   800
#define IMW   800
#define BLOCKS_PER_DET 3    // 3 blocks x 256 thr = 768 >= 784 (stride tail in block rem==0)
#define NBLK (N_DET * BLOCKS_PER_DET)   // 1536
#define IOU_THRESH 0.5f
#define EPS_F 1e-7f

// ws layout — NO pre-zeroing needed (every slot read by `final` is written by
// `fused` in the same launch; no atomics, no read-modify-write of poison):
//   wsf[0 .. 1535]        : per-block partial |diff| sums (0 for invalid dets)
//   wsi[1536 .. 2047]     : per-detection valid flag (0/1), written by rem==0 block
#define FLAG_BASE NBLK

// ---------------- Kernel 1: fused IOU/argmax + bilinear crop + |diff| partials ----
__global__ __launch_bounds__(256) void fused_maskloss(
    const float* __restrict__ det,    // (512,4)  x1,y1,x2,y2
    const float* __restrict__ masks,  // (512,28,28,100)
    const float* __restrict__ ann,    // (100,4)
    const float* __restrict__ mt,     // (100,800,800)
    float* __restrict__ wsf,
    int*   __restrict__ wsi)
{
    __shared__ float sv[256];
    __shared__ int   si[256];

    const int b   = blockIdx.x;
    const int n   = b / BLOCKS_PER_DET;
    const int rem = b - n * BLOCKS_PER_DET;
    const int tid = threadIdx.x;

    const float dx1 = det[n * 4 + 0];
    const float dy1 = det[n * 4 + 1];
    const float dx2 = det[n * 4 + 2];
    const float dy2 = det[n * 4 + 3];

    // ---- IOU: thread k handles annotation k (K=100 < 256) ----
    float best = -1.0f;
    int   bidx = 0x7FFFFFFF;
    if (tid < K_ANN) {
        const float ax1 = ann[tid * 4 + 0];
        const float ay1 = ann[tid * 4 + 1];
        const float ax2 = ann[tid * 4 + 2];
        const float ay2 = ann[tid * 4 + 3];
        const float area_k = (ax2 - ax1) * (ay2 - ay1);
        float iw = fminf(dx2, ax2) - fmaxf(dx1, ax1);
        float ih = fminf(dy2, ay2) - fmaxf(dy1, ay1);
        iw = fmaxf(iw, 0.0f);
        ih = fmaxf(ih, 0.0f);
        const float inter = iw * ih;
        const float ua = (dx2 - dx1) * (dy2 - dy1) + area_k - inter;
        best = inter / fmaxf(ua, EPS_F);
        bidx = tid;
    }

    sv[tid] = best;
    si[tid] = bidx;
    __syncthreads();
    // argmax reduce; ties -> smaller index (jnp.argmax semantics)
    for (int s = 128; s > 0; s >>= 1) {
        if (tid < s) {
            const float ov = sv[tid + s];
            const int   oi = si[tid + s];
            if (ov > sv[tid] || (ov == sv[tid] && oi < si[tid])) {
                sv[tid] = ov;
                si[tid] = oi;
            }
        }
        __syncthreads();
    }
    const float max_iou = sv[0];
    const int   k       = si[0];
    __syncthreads();  // before sv[] reuse below

    const bool valid = (max_iou >= IOU_THRESH);
    if (tid == 0) {
        if (rem == 0) wsi[FLAG_BASE + n] = valid ? 1 : 0;
        if (!valid)   wsf[b] = 0.0f;     // partial must still be written
    }
    if (!valid) return;

    // ---- boxes = [y1/H, x1/W, y2/H, x2/W] ----
    const float by1 = dy1 / (float)IMH;
    const float bx1 = dx1 / (float)IMW;
    const float by2 = dy2 / (float)IMH;
    const float bx2 = dx2 / (float)IMW;

    const float* __restrict__ img = mt + (size_t)k * (IMH * IMW);
    const float* __restrict__ msk = masks + (size_t)n * NPIX * K_ANN + k;

    float local = 0.0f;
    for (int p = rem * 256 + tid; p < NPIX; p += BLOCKS_PER_DET * 256) {
        const int i = p / MW;
        const int j = p - i * MW;
        const float gy = (float)i * (1.0f / (float)(MH - 1));
        const float gx = (float)j * (1.0f / (float)(MW - 1));
        const float in_y = (by1 + (by2 - by1) * gy) * (float)(IMH - 1);
        const float in_x = (bx1 + (bx2 - bx1) * gx) * (float)(IMW - 1);
        const bool vy = (in_y >= 0.0f) && (in_y <= (float)(IMH - 1));
        const bool vx = (in_x >= 0.0f) && (in_x <= (float)(IMW - 1));
        const float y0f = floorf(in_y);
        const float x0f = floorf(in_x);
        const float yf = in_y - y0f;
        const float xf = in_x - x0f;
        int y0i = (int)y0f;
        int x0i = (int)x0f;
        y0i = min(max(y0i, 0), IMH - 1);
        x0i = min(max(x0i, 0), IMW - 1);
        const int y1i = min(y0i + 1, IMH - 1);
        const int x1i = min(x0i + 1, IMW - 1);

        const float v00 = img[y0i * IMW + x0i];
        const float v01 = img[y0i * IMW + x1i];
        const float v10 = img[y1i * IMW + x0i];
        const float v11 = img[y1i * IMW + x1i];
        const float top = v00 + (v01 - v00) * xf;
        const float bot = v10 + (v11 - v10) * xf;
        float outv = top + (bot - top) * yf;
        outv = (vy && vx) ? outv : 0.0f;

        const float msel = msk[(size_t)p * K_ANN];  // masks[n, i, j, k]
        local += fabsf(msel - outv);
    }

    // wave shuffle reduce then cross-wave via LDS; plain store (no atomic)
    for (int off = 32; off > 0; off >>= 1)
        local += __shfl_down(local, off);
    __shared__ float wsum[4];
    const int wave = tid >> 6;
    const int lane = tid & 63;
    if (lane == 0) wsum[wave] = local;
    __syncthreads();
    if (tid == 0)
        wsf[b] = (wsum[0] + wsum[1]) + (wsum[2] + wsum[3]);
}

// ---------------- Kernel 2: reduce partials + finalize ----------------
__global__ __launch_bounds__(256) void maskloss_final(
    const float* __restrict__ wsf,
    const int*   __restrict__ wsi,
    float* __restrict__ out)
{
    const int tid = threadIdx.x;

    float s = 0.0f;
    #pragma unroll
    for (int i = 0; i < NBLK / 256; ++i)        // 6 * 256 = 1536
        s += wsf[tid + i * 256];

    int c = wsi[FLAG_BASE + tid] + wsi[FLAG_BASE + 256 + tid];

    for (int off = 32; off > 0; off >>= 1) {
        s += __shfl_down(s, off);
        c += __shfl_down(c, off);
    }
    __shared__ float ssum[4];
    __shared__ int   scnt[4];
    const int wave = tid >> 6;
    const int lane = tid & 63;
    if (lane == 0) { ssum[wave] = s; scnt[wave] = c; }
    __syncthreads();
    if (tid == 0) {
        const float total = (ssum[0] + ssum[1]) + (ssum[2] + ssum[3]);
        const float cnt   = (float)(scnt[0] + scnt[1] + scnt[2] + scnt[3]);
        out[0] = total / fmaxf(cnt * (float)NPIX, 1.0f);
    }
}

extern "C" void kernel_launch(void* const* d_in, const int* in_sizes, int n_in,
                              void* d_out, int out_size, void* d_ws, size_t ws_size,
                              hipStream_t stream) {
    const float* det   = (const float*)d_in[0];  // detections (1,512,4)
    const float* masks = (const float*)d_in[1];  // masks (1,512,28,28,100)
    const float* ann   = (const float*)d_in[2];  // annotations (1,100,4)
    const float* mt    = (const float*)d_in[3];  // masks_target (1,100,800,800)
    float* out = (float*)d_out;
    float* wsf = (float*)d_ws;
    int*   wsi = (int*)d_ws;

    fused_maskloss<<<NBLK, 256, 0, stream>>>(det, masks, ann, mt, wsf, wsi);
    maskloss_final<<<1, 256, 0, stream>>>(wsf, wsi, out);
}